// Round 3
// baseline (76.864 us; speedup 1.0000x reference)
//
#include <hip/hip_runtime.h>
#include <stdint.h>

#define F_FIELDS 17
#define HH 300
#define WW 400
#define H_F 38
#define W_F 50
#define PTS_PER_FIELD (H_F * W_F)     // 1900
#define RAD 13

// Block = 32x32 pixel region, binned into 4x4 tiles of 8x8.
// 256 threads = 4 waves; each wave owns a 16x16 quadrant = four 8x8 tiles
// processed sequentially with ONE pixel per lane (64 lanes = 8x8).
//
// Round-2 model: dur_us ~= 66-68 us harness floor (268 MB poison fill at
// ~43 us + small-dispatch overhead) + ~5-7 us kernel. Remaining kernel cost
// theory: phase-1 insertion (divergent <=16-deep nested loop, ~400 LDS
// atomicAdds/block over 16 counters with same-address serialization) and
// serialized per-tile cifhr load latency in phase 2.
// This round: ballot-based insertion (1 atomic per wave per tile, mbcnt
// prefix slots, uniform 16-iter loop) + prefetch all 4 cifhr loads.
#define GX 13
#define GY 10
#define NT 16      // 4x4 tiles per block
#define CAP 48     // per-tile list cap; mean n ~= 8.4, hard bound ~25-30
// LDS: 16*48*(16+4) + 64 = 15.4 KB -> 8 blocks/CU (wave-slot limited).

__global__ __launch_bounds__(256) void cifhr_fused_kernel(
    const float* __restrict__ x, const float* __restrict__ cifhr,
    float* __restrict__ out) {
    __shared__ float4 sA[NT][CAP];   // px, py, value(=v/16), c(=-1/(16*sigma2))
    __shared__ float  sB[NT][CAP];   // trunc2 = 4*sigma2 (exact, bit-matches ref cmp)
    __shared__ int    cnt[NT];

    const int tid = threadIdx.x;
    const int ln  = tid & 63;
    const int f  = blockIdx.z;
    const int X0 = blockIdx.x * 32;
    const int Y0 = blockIdx.y * 32;
    const int xvhi = min(X0 + 31, WW - 1);
    const int yvhi = min(Y0 + 31, HH - 1);
    const int txmax = (xvhi - X0) >> 3;   // 0..3 (clips tiles past image edge)
    const int tymax = (yvhi - Y0) >> 3;

    if (tid < NT) cnt[tid] = 0;
    __syncthreads();

    // ---- Phase 1: 16x16 grid-neighborhood scan, one point per thread ----
    // Scan window keeps >=8.9 sigma jitter margin (P~2e-19/point of missing
    // a reachable point); the exact per-point bbox test below is the filter.
    const float* base = x + (size_t)(f * 5) * PTS_PER_FIELD;
    const int jlo = (X0 >> 3) - 6;            // X0 % 32 == 0 -> exact X0/8
    const int ilo = (Y0 >> 3) - 6;
    const int i = ilo + (tid >> 4);
    const int j = jlo + (tid & 15);
    const bool ok = (i >= 0) & (i < H_F) & (j >= 0) & (j < W_F);
    const int p = ok ? (i * W_F + j) : 0;      // clamped when unused

    float v = 0.f, xr = 0.f, yr = 0.f, sc = 0.f;
    if (ok) {                                  // 4 independent loads, one batch
        v  = base[p];
        xr = base[PTS_PER_FIELD + p];
        yr = base[2 * PTS_PER_FIELD + p];
        sc = base[4 * PTS_PER_FIELD + p];
    }

    // Per-lane 16-bit tile-membership mask (bit t = tile t gets this point).
    unsigned int tmask = 0u;
    float4 rec = make_float4(0.f, 0.f, 0.f, 0.f);
    float tr = 0.f;
    if (ok && (v >= 0.1f) && (sc * 8.0f >= 0.0f)) {   // V_TH, MIN_SCALE
        float px = xr * 8.0f;                  // STRIDE = 8 (exact pow2)
        float py = yr * 8.0f;
        int cx = (int)rintf(px);               // jnp.round = half-even
        int cy = (int)rintf(py);
        float sigma  = fmaxf(1.0f, 4.0f * sc); // 0.5*scale*8
        float sigma2 = sigma * sigma;
        // d2 <= 4*sigma^2 needs |xx-cx| <= floor(2*sigma+0.5); cap at 13
        int rp = min(RAD, (int)(2.0f * sigma + 0.5f));
        int xlo = cx - rp, xhi = cx + rp;
        int ylo = cy - rp, yhi = cy + rp;
        if (!(xhi < X0 || xlo > xvhi || yhi < Y0 || ylo > yvhi)) {
            int tx0 = max(0, (xlo - X0) >> 3), tx1 = min(txmax, (xhi - X0) >> 3);
            int ty0 = max(0, (ylo - Y0) >> 3), ty1 = min(tymax, (yhi - Y0) >> 3);
            // colm: bits tx0..tx1; spread rows to nibble positions 4*ty.
            unsigned int colm = (((2u << tx1) - 1u) & ~((1u << tx0) - 1u));
            unsigned int spread = 0u;
            for (int r = ty0; r <= ty1; ++r) spread |= (1u << (4 * r));
            tmask = colm * spread;             // 16-bit tile mask
            rec = make_float4(px, py, v * 0.0625f, -1.0f / (16.0f * sigma2));
            tr = 4.0f * sigma2;
        }
    }

    // Uniform 16-iteration insertion: one ballot + (at most) one LDS atomic
    // per wave per tile; slots via mbcnt prefix; parallel ds_writes.
    #pragma unroll 4
    for (int t = 0; t < NT; ++t) {
        bool ins = (tmask >> t) & 1u;
        uint64_t m = __ballot(ins);
        if (m) {                                // wave-uniform condition
            int lead = __ffsll((long long)m) - 1;
            int nw   = __popcll(m);
            int bse  = 0;
            if (ln == lead) bse = atomicAdd(&cnt[t], nw);
            bse = __shfl(bse, lead, 64);
            if (ins) {
                unsigned int lo = __builtin_amdgcn_mbcnt_lo((uint32_t)m, 0u);
                unsigned int pre = __builtin_amdgcn_mbcnt_hi((uint32_t)(m >> 32), lo);
                int slot = bse + (int)pre;
                if (slot < CAP) { sA[t][slot] = rec; sB[t][slot] = tr; }
            }
        }
    }
    __syncthreads();

    // ---- Phase 2: wave -> 16x16 quadrant = four 8x8 tiles, 1 px/lane ----
    const int s  = tid >> 6;
    const int sx = s & 1, sy = s >> 1;
    const int lx = ln & 7, ly = ln >> 3;

    // Prefetch all 4 cifhr values (independent loads, latency overlapped).
    float  cpre[4];
    size_t idxp[4];
    bool   wvp[4], val[4];
    #pragma unroll
    for (int q = 0; q < 4; ++q) {
        const int tX = (sx << 1) | (q & 1);
        const int tY = (sy << 1) | (q >> 1);
        val[q] = (tX <= txmax) & (tY <= tymax);
        const int xb = X0 + (tX << 3) + lx;       // xb < WW always (WW%8==0)
        const int yb = Y0 + (tY << 3) + ly;
        wvp[q] = val[q] & (yb < HH);              // HH%8 != 0 -> guard rows
        idxp[q] = ((size_t)f * HH + yb) * WW + xb;
        cpre[q] = wvp[q] ? cifhr[idxp[q]] : 0.0f;
    }

    #pragma unroll
    for (int q = 0; q < 4; ++q) {
        if (!val[q]) continue;                    // wave-uniform
        const int tX = (sx << 1) | (q & 1);
        const int tY = (sy << 1) | (q >> 1);
        const int t = tY * 4 + tX;
        const int n = min(cnt[t], CAP);           // wave-uniform

        const float xf = (float)(X0 + (tX << 3) + lx);
        const float yf = (float)(Y0 + (tY << 3) + ly);

        float acc = 0.0f;
        for (int k = 0; k < n; ++k) {
            float4 a  = sA[t][k];                 // uniform addr: ds broadcast
            float  trc = sB[t][k];
            float dx = xf - a.x, dy = yf - a.y;
            float dx2 = dx * dx, dy2 = dy * dy;
            float d2 = dy2 + dx2;                 // ref add order dy2 + dx2
            float u = fmaf(a.w, d2, 1.0f);        // (1 - d2/(16*s2))
            u *= u; u *= u; u *= u;               // ^8
            float g   = (fmaxf(dy2, dx2) < 0.25f) ? 1.0f : u;   // nearest
            float sel = (d2 <= trc) ? a.z : 0.0f; // exact cutoff cmp vs staged tr
            acc = fmaf(sel, g, acc);
        }
        if (wvp[q]) out[idxp[q]] = fminf(acc + cpre[q], 1.0f);
    }
}

extern "C" void kernel_launch(void* const* d_in, const int* in_sizes, int n_in,
                              void* d_out, int out_size, void* d_ws, size_t ws_size,
                              hipStream_t stream) {
    const float* cifhr = (const float*)d_in[0];
    const float* x     = (const float*)d_in[1];
    float* outp = (float*)d_out;

    dim3 grid(GX, GY, F_FIELDS);   // 13 x 10 x 17 = 2210 blocks
    cifhr_fused_kernel<<<grid, 256, 0, stream>>>(x, cifhr, outp);
}

// Round 4
// 73.584 us; speedup vs baseline: 1.0446x; 1.0446x over previous
//
#include <hip/hip_runtime.h>
#include <stdint.h>

#define F_FIELDS 17
#define HH 300
#define WW 400
#define H_F 38
#define W_F 50
#define PTS_PER_FIELD (H_F * W_F)     // 1900
#define RAD 13

// Block = 32x32 pixel region, binned into 4x4 tiles of 8x8.
// 256 threads = 4 waves; each wave owns a 16x16 quadrant = four 8x8 tiles
// processed sequentially with ONE pixel per lane (64 lanes = 8x8).
//
// Round-4: A/B revert. Round-2 (divergent insertion, 73.55 us) beat
// round-3 (ballot insertion, 76.86 us): the uniform 16-iter ballot loop
// (~190 wave-inst incl. ds_bpermute shfl) costs more than the divergent
// nested loop (~10-12 iters of a 6-inst body; only ~2-3 same-address
// atomic collisions per counter per wave). This round restores the r2
// insertion exactly and keeps only the independently-sound r3 piece:
// prefetching the 4 cifhr loads (4 independent ~300cy loads in flight
// instead of serialized one-per-tile).
//
// Cost model (consistent r0->r2->r3): dur_us ~= 42 us poison fill
// + ~25 us fixed reset/small-dispatch overhead + ~7 us kernel
// (issue-bound, ~2 VALU inst/px in phase 2).
#define GX 13
#define GY 10
#define NT 16      // 4x4 tiles per block
#define CAP 48     // per-tile list cap; mean n ~= 8.4, hard bound ~25-30
// LDS: 16*48*(16+4) + 64 = 15.4 KB -> 8 blocks/CU (wave-slot limited).

__global__ __launch_bounds__(256) void cifhr_fused_kernel(
    const float* __restrict__ x, const float* __restrict__ cifhr,
    float* __restrict__ out) {
    __shared__ float4 sA[NT][CAP];   // px, py, value(=v/16), c(=-1/(16*sigma2))
    __shared__ float  sB[NT][CAP];   // trunc2 = 4*sigma2 (exact, bit-matches ref cmp)
    __shared__ int    cnt[NT];

    const int tid = threadIdx.x;
    const int ln  = tid & 63;
    const int f  = blockIdx.z;
    const int X0 = blockIdx.x * 32;
    const int Y0 = blockIdx.y * 32;
    const int xvhi = min(X0 + 31, WW - 1);
    const int yvhi = min(Y0 + 31, HH - 1);
    const int txmax = (xvhi - X0) >> 3;   // 0..3 (clips tiles past image edge)
    const int tymax = (yvhi - Y0) >> 3;

    if (tid < NT) cnt[tid] = 0;
    __syncthreads();

    // ---- Phase 1: 16x16 grid-neighborhood scan, one point per thread ----
    // Scan window keeps >=8.9 sigma jitter margin (P~2e-19/point of missing
    // a reachable point); the exact per-point bbox test below is the filter.
    const float* base = x + (size_t)(f * 5) * PTS_PER_FIELD;
    const int jlo = (X0 >> 3) - 6;            // X0 % 32 == 0 -> exact X0/8
    const int ilo = (Y0 >> 3) - 6;
    const int i = ilo + (tid >> 4);
    const int j = jlo + (tid & 15);
    const bool ok = (i >= 0) & (i < H_F) & (j >= 0) & (j < W_F);
    const int p = ok ? (i * W_F + j) : 0;      // clamped when unused

    float v = 0.f, xr = 0.f, yr = 0.f, sc = 0.f;
    if (ok) {                                  // 4 independent loads, one batch
        v  = base[p];
        xr = base[PTS_PER_FIELD + p];
        yr = base[2 * PTS_PER_FIELD + p];
        sc = base[4 * PTS_PER_FIELD + p];
    }
    if (ok && (v >= 0.1f) && (sc * 8.0f >= 0.0f)) {   // V_TH, MIN_SCALE
        float px = xr * 8.0f;                  // STRIDE = 8 (exact pow2)
        float py = yr * 8.0f;
        int cx = (int)rintf(px);               // jnp.round = half-even
        int cy = (int)rintf(py);
        float sigma  = fmaxf(1.0f, 4.0f * sc); // 0.5*scale*8
        float sigma2 = sigma * sigma;
        // d2 <= 4*sigma^2 needs |xx-cx| <= floor(2*sigma+0.5); cap at 13
        int rp = min(RAD, (int)(2.0f * sigma + 0.5f));
        int xlo = cx - rp, xhi = cx + rp;
        int ylo = cy - rp, yhi = cy + rp;
        if (!(xhi < X0 || xlo > xvhi || yhi < Y0 || ylo > yvhi)) {
            int tx0 = max(0, (xlo - X0) >> 3), tx1 = min(txmax, (xhi - X0) >> 3);
            int ty0 = max(0, (ylo - Y0) >> 3), ty1 = min(tymax, (yhi - Y0) >> 3);
            float4 rec = make_float4(px, py, v * 0.0625f,
                                     -1.0f / (16.0f * sigma2));
            float tr = 4.0f * sigma2;
            for (int ty = ty0; ty <= ty1; ++ty)
                for (int tx = tx0; tx <= tx1; ++tx) {
                    int t = ty * 4 + tx;
                    int slot = atomicAdd(&cnt[t], 1);   // LDS atomic
                    if (slot < CAP) { sA[t][slot] = rec; sB[t][slot] = tr; }
                }
        }
    }
    __syncthreads();

    // ---- Phase 2: wave -> 16x16 quadrant = four 8x8 tiles, 1 px/lane ----
    const int s  = tid >> 6;
    const int sx = s & 1, sy = s >> 1;
    const int lx = ln & 7, ly = ln >> 3;

    // Prefetch all 4 cifhr values (independent loads, latency overlapped).
    float  cpre[4];
    size_t idxp[4];
    bool   wvp[4], val[4];
    #pragma unroll
    for (int q = 0; q < 4; ++q) {
        const int tX = (sx << 1) | (q & 1);
        const int tY = (sy << 1) | (q >> 1);
        val[q] = (tX <= txmax) & (tY <= tymax);
        const int xb = X0 + (tX << 3) + lx;       // xb < WW always (WW%8==0)
        const int yb = Y0 + (tY << 3) + ly;
        wvp[q] = val[q] & (yb < HH);              // HH%8 != 0 -> guard rows
        idxp[q] = ((size_t)f * HH + yb) * WW + xb;
        cpre[q] = wvp[q] ? cifhr[idxp[q]] : 0.0f;
    }

    #pragma unroll
    for (int q = 0; q < 4; ++q) {
        if (!val[q]) continue;                    // wave-uniform
        const int tX = (sx << 1) | (q & 1);
        const int tY = (sy << 1) | (q >> 1);
        const int t = tY * 4 + tX;
        const int n = min(cnt[t], CAP);           // wave-uniform

        const float xf = (float)(X0 + (tX << 3) + lx);
        const float yf = (float)(Y0 + (tY << 3) + ly);

        float acc = 0.0f;
        for (int k = 0; k < n; ++k) {
            float4 a  = sA[t][k];                 // uniform addr: ds broadcast
            float  trc = sB[t][k];
            float dx = xf - a.x, dy = yf - a.y;
            float dx2 = dx * dx, dy2 = dy * dy;
            float d2 = dy2 + dx2;                 // ref add order dy2 + dx2
            float u = fmaf(a.w, d2, 1.0f);        // (1 - d2/(16*s2))
            u *= u; u *= u; u *= u;               // ^8
            float g   = (fmaxf(dy2, dx2) < 0.25f) ? 1.0f : u;   // nearest
            float sel = (d2 <= trc) ? a.z : 0.0f; // exact cutoff cmp vs staged tr
            acc = fmaf(sel, g, acc);
        }
        if (wvp[q]) out[idxp[q]] = fminf(acc + cpre[q], 1.0f);
    }
}

extern "C" void kernel_launch(void* const* d_in, const int* in_sizes, int n_in,
                              void* d_out, int out_size, void* d_ws, size_t ws_size,
                              hipStream_t stream) {
    const float* cifhr = (const float*)d_in[0];
    const float* x     = (const float*)d_in[1];
    float* outp = (float*)d_out;

    dim3 grid(GX, GY, F_FIELDS);   // 13 x 10 x 17 = 2210 blocks
    cifhr_fused_kernel<<<grid, 256, 0, stream>>>(x, cifhr, outp);
}